// Round 5
// baseline (187.805 us; speedup 1.0000x reference)
//
#include <hip/hip_runtime.h>
#include <hip/hip_bf16.h>

typedef unsigned short u16;
typedef unsigned int u32;
typedef __attribute__((ext_vector_type(8))) __bf16 bf16x8;
typedef __attribute__((ext_vector_type(4))) float f32x4;

#define KCTX 32
#define INF_ 608
#define HID_ 384
#define NBOX 16384

// ws layout (bytes).
#define AW_OFF  0                     // aw  [16384][32] float2 = 4,194,304
#define CNT_OFF 4194304               // cnt [16384] i32        =    65,536
#define WH_OFF  19922944              // Wh2 [8][16384][48] bf16 = 12,582,912 (slice-major)
#define BT_OFF  32505856              // Bt  [384,608]  bf16 =    466,944
#define V_OFF   32972800              // v   [608] f32        =      2,432
#define SI_OFF  32975232              // si  [16384] f32      =     65,536
#define SJ_OFF  33040768              // sj  [16384] f32      =     65,536
#define AJF_OFF 33106304              // ajf [384] f32        =      1,536
#define ABF_OFF 33107840              // abf [1] f32

__device__ __forceinline__ float bfu(u16 u)  { return __uint_as_float(((u32)u) << 16); }
__device__ __forceinline__ float bflo(u32 u) { return __uint_as_float(u << 16); }
__device__ __forceinline__ float bfhi(u32 u) { return __uint_as_float(u & 0xffff0000u); }
__device__ __forceinline__ u16 f2bf(float x) {            // round-to-nearest-even
  u32 u = __float_as_uint(x);
  return (u16)((u + 0x7fffu + ((u >> 16) & 1u)) >> 16);
}

// ---- per-wave runtime dtype detection (wave-uniform, L2-hot; validated r2-r8) ----
__device__ __forceinline__ int detect_f32(const u32* hw) {
  const u32 w = hw[threadIdx.x & 63];
  const int e = (int)((w >> 7) & 0xffu);
  const unsigned long long mb = __ballot(e > 134 || e < 100);
  return __popcll(mb) >= 16;
}
__device__ __forceinline__ int detect_i64(const int* ci) {
  const int hi = ci[2 * (threadIdx.x & 63) + 1];
  const unsigned long long mz = __ballot(hi == 0 || hi == -1);
  return __popcll(mz) >= 48;
}

// ---- prep: Bt = bf16(W_j^T), v = W_i@a_i, ajf/abf fp32 (unchanged) ----
__global__ __launch_bounds__(256) void prep_kernel(
    const void* __restrict__ h, const void* __restrict__ Wi,
    const void* __restrict__ Wj, const void* __restrict__ ai,
    const void* __restrict__ aj, const void* __restrict__ ab,
    u16* __restrict__ Bt, float* __restrict__ v,
    float* __restrict__ ajf, float* __restrict__ abf) {
  __shared__ u16 tile[64][65];
  const int f32m = detect_f32((const u32*)h);
  const int bid = blockIdx.x, tid = threadIdx.x;
  if (bid < 60) {                                  // transpose: 10(f) x 6(h) tiles
    const int ft = bid / 6, ht = bid - ft * 6;
    const int f0 = ft * 64, h0 = ht * 64;
    const int ln = tid & 63, fg = tid >> 6;
#pragma unroll
    for (int rr = 0; rr < 16; ++rr) {
      const int fl = fg * 16 + rr;
      const int f = f0 + fl;
      if (f < INF_)
        tile[fl][ln] = f32m ? f2bf(((const float*)Wj)[(size_t)f * HID_ + h0 + ln])
                            : ((const u16*)Wj)[(size_t)f * HID_ + h0 + ln];
    }
    __syncthreads();
#pragma unroll
    for (int rr = 0; rr < 16; ++rr) {
      const int hl = fg * 16 + rr;
      const int f = f0 + ln;
      if (f < INF_) Bt[(size_t)(h0 + hl) * INF_ + f] = tile[ln][hl];
    }
  } else if (bid < 98) {                           // v: 16-lane group per row
    const int t = (bid - 60) * 16 + (tid >> 4);
    const int sl = tid & 15;
    if (t < INF_) {
      float s = 0.f;
      if (f32m) {
        const float4* wi = (const float4*)((const float*)Wi + (size_t)t * HID_);
        const float4* a4 = (const float4*)ai;
        for (int c = sl; c < 96; c += 16) {
          float4 x = wi[c], y = a4[c];
          s += x.x * y.x + x.y * y.y + x.z * y.z + x.w * y.w;
        }
      } else {
        const uint4* wi = (const uint4*)((const u16*)Wi + (size_t)t * HID_);
        const uint4* a4 = (const uint4*)ai;
        for (int c = sl; c < 48; c += 16) {
          uint4 x = wi[c], y = a4[c];
          s += bflo(x.x) * bflo(y.x) + bfhi(x.x) * bfhi(y.x)
             + bflo(x.y) * bflo(y.y) + bfhi(x.y) * bfhi(y.y)
             + bflo(x.z) * bflo(y.z) + bfhi(x.z) * bfhi(y.z)
             + bflo(x.w) * bflo(y.w) + bfhi(x.w) * bfhi(y.w);
        }
      }
      s += __shfl_xor(s, 1); s += __shfl_xor(s, 2);
      s += __shfl_xor(s, 4); s += __shfl_xor(s, 8);
      if (sl == 0) v[t] = s;
    }
  } else {                                         // ajf/abf only
    for (int j = tid; j < HID_; j += 256)
      ajf[j] = f32m ? ((const float*)aj)[j] : bfu(((const u16*)aj)[j]);
    if (tid == 0)
      abf[0] = f32m ? ((const float*)ab)[0] : bfu(((const u16*)ab)[0]);
  }
}

// ---- gemm v3: barrier-free, LDS-free, high-occupancy. r1 counters (the only
// per-kernel evidence): 43.6us @ MfmaUtil 6%, VALUBusy 7%, Occ 18.7% -> pure
// stall at 8 waves/CU with a vmcnt(0)+barrier drain per K-step. Both MFMA
// operands are 16B-contiguous in memory (h rows and Bt rows are [.][K]), so
// load fragments DIRECTLY global->VGPR: no LDS, no barriers, no staging.
// 1024 blocks x 256 thr; block = 16 rows x 384 cols; wave wv covers cols
// [96wv, 96wv+96). <=128 VGPR -> 4 blk/CU = 16 waves/CU (50% occ). Bt is
// per-XCD-L2-resident (467 KB); L2 floor ~16us vs 43 measured. si fused
// (redundant per wave, cheap); sj via 256B LDS + single end barrier. ----
__global__ __launch_bounds__(256, 4) void gemm_fused(
    const void* __restrict__ A, const u16* __restrict__ Bt,
    const float* __restrict__ v, u16* __restrict__ C,
    float* __restrict__ si, const float* __restrict__ ajf,
    float* __restrict__ sj) {
  __shared__ float sjred[4][16];
  const int f32m = detect_f32((const u32*)A);
  const int tid  = threadIdx.x;
  const int lane = tid & 63;
  const int wv   = tid >> 6;                       // 0..3
  const int lm   = lane & 15;                      // fragment row / col
  const int q    = lane >> 4;                      // 0..3: k-subslice
  const int row0 = blockIdx.x * 16;
  const int n0   = wv * 96;

  const float4* v4 = (const float4*)v;
  // per-lane A base: row (row0+lm), k-offset q*8
  const float* hf = (const float*)A + (size_t)(row0 + lm) * INF_;
  const u16*   hb = (const u16*)A   + (size_t)(row0 + lm) * INF_;

  // per-lane B bases: col n0+in*16+lm, k-offset q*8
  const u16* bbase = Bt + (size_t)(n0 + lm) * INF_ + q * 8;

  f32x4 acc[6];
#pragma unroll
  for (int j = 0; j < 6; ++j) acc[j] = (f32x4){0.f, 0.f, 0.f, 0.f};
  float sacc = 0.f;

  for (int kt = 0; kt < 19; ++kt) {
    const int k0 = kt * 32 + q * 8;                // this lane's 8-k window
    bf16x8 af;
    {
      const int c4 = k0 >> 2;                      // float4 index
      const float4 w0 = v4[c4], w1 = v4[c4 + 1];
      if (f32m) {
        const float4 x0 = *(const float4*)(hf + k0);
        const float4 x1 = *(const float4*)(hf + k0 + 4);
        uint4 pk;
        pk.x = (u32)f2bf(x0.x) | ((u32)f2bf(x0.y) << 16);
        pk.y = (u32)f2bf(x0.z) | ((u32)f2bf(x0.w) << 16);
        pk.z = (u32)f2bf(x1.x) | ((u32)f2bf(x1.y) << 16);
        pk.w = (u32)f2bf(x1.z) | ((u32)f2bf(x1.w) << 16);
        af = __builtin_bit_cast(bf16x8, pk);
        sacc += x0.x * w0.x + x0.y * w0.y + x0.z * w0.z + x0.w * w0.w
              + x1.x * w1.x + x1.y * w1.y + x1.z * w1.z + x1.w * w1.w;
      } else {
        const uint4 xb = *(const uint4*)(hb + k0);
        af = __builtin_bit_cast(bf16x8, xb);
        sacc += bflo(xb.x) * w0.x + bfhi(xb.x) * w0.y
              + bflo(xb.y) * w0.z + bfhi(xb.y) * w0.w
              + bflo(xb.z) * w1.x + bfhi(xb.z) * w1.y
              + bflo(xb.w) * w1.z + bfhi(xb.w) * w1.w;
      }
    }
    bf16x8 bfr[6];
#pragma unroll
    for (int in = 0; in < 6; ++in)
      bfr[in] = *(const bf16x8*)(bbase + (size_t)in * 16 * INF_ + kt * 32);
#pragma unroll
    for (int in = 0; in < 6; ++in)
      acc[in] = __builtin_amdgcn_mfma_f32_16x16x32_bf16(af, bfr[in], acc[in], 0, 0, 0);
  }

  // si: rows are wave-redundant; reduce q-groups, wave 0 writes
  sacc += __shfl_xor(sacc, 16);
  sacc += __shfl_xor(sacc, 32);
  if (wv == 0 && lane < 16) si[row0 + lane] = sacc;

  // C write, slice-major Wh2[s][row][48]; col = n0+in*16+lm
#pragma unroll
  for (int in = 0; in < 6; ++in) {
    const int col = n0 + in * 16 + lm;
    const int s = col / 48, cw = col - s * 48;
#pragma unroll
    for (int r = 0; r < 4; ++r) {
      const int rowg = row0 + q * 4 + r;
      C[((size_t)s * NBOX + rowg) * 48 + cw] = f2bf(acc[in][r]);
    }
  }

  // sj: p[row] = sum_col acc*ajf over this wave's 96 cols; 16-lane reduce,
  // tiny LDS cross-wave sum (single barrier at kernel end only)
  float ajv[6];
#pragma unroll
  for (int in = 0; in < 6; ++in) ajv[in] = ajf[n0 + in * 16 + lm];
#pragma unroll
  for (int r = 0; r < 4; ++r) {
    float p = acc[0][r] * ajv[0] + acc[1][r] * ajv[1] + acc[2][r] * ajv[2]
            + acc[3][r] * ajv[3] + acc[4][r] * ajv[4] + acc[5][r] * ajv[5];
    p += __shfl_xor(p, 1); p += __shfl_xor(p, 2);
    p += __shfl_xor(p, 4); p += __shfl_xor(p, 8);
    if (lm == 0) sjred[wv][q * 4 + r] = p;
  }
  __syncthreads();
  if (tid < 16)
    sj[row0 + tid] = sjred[0][tid] + sjred[1][tid] + sjred[2][tid] + sjred[3][tid];
}

// ---- score: softmax weights once per row, compacted (ballot prefix),
// padded to multiple of 4 with (w=0, idx=0). 2048 blocks x 256 thr, 8 rows/blk. ----
__global__ __launch_bounds__(256) void score_kernel(
    const int* __restrict__ ci, const float* __restrict__ si,
    const float* __restrict__ sj, const float* __restrict__ abf,
    float2* __restrict__ aw, int* __restrict__ cnt) {
  const int i64 = detect_i64(ci);
  const int tid = threadIdx.x;
  const int k = tid & 31;
  const int n = blockIdx.x * 8 + (tid >> 5);       // 2048*8 = 16384 exactly
  const size_t t = (size_t)n * KCTX + k;
  int idx;
  if (i64) { int lo = ci[2 * t], hi2 = ci[2 * t + 1]; idx = (hi2 < 0) ? -1 : lo; }
  else     { idx = ci[t]; }
  const bool valid = idx >= 0;
  const float sjv = valid ? sj[idx] : 0.f;
  float raw = si[n] + sjv + abf[0];
  float lr = raw > 0.f ? raw : 0.2f * raw;
  float s = valid ? lr : -9e15f;
  float m = s;
#pragma unroll
  for (int o = 16; o; o >>= 1) m = fmaxf(m, __shfl_xor(m, o, 32));
  float p = __expf(s - m);
  float d = p;
#pragma unroll
  for (int o = 16; o; o >>= 1) d += __shfl_xor(d, o, 32);
  const float w = p / d;                           // invalid: p==0 => w==0
  const unsigned long long bm = __ballot(valid);
  const u32 m32 = (u32)(bm >> (tid & 32));         // this 32-group's mask
  const int c_ = __popc(m32);
  const int r4 = (c_ + 3) & ~3;                    // pad to multiple of 4
  if (valid) {
    const int pf = __popc(m32 & ((1u << k) - 1u));
    aw[(size_t)n * KCTX + pf] = (float2){w, __int_as_float(idx)};
  }
  if (k >= c_ && k < r4) aw[(size_t)n * KCTX + k] = (float2){0.f, 0.f};
  if (k == 0) cnt[n] = r4;
}

// ---- gather: XCD-partitioned slices (r4, unchanged). 2048 blocks x 384 thr;
// slice s = blockIdx&7, rows g0..g0+63; each block reads only Wh2[s]
// (1.57 MB, per-XCD-L2-resident). ----
__global__ __launch_bounds__(384) void gather_kernel(
    const void* __restrict__ h, const float2* __restrict__ aw,
    const int* __restrict__ cnt, const u16* __restrict__ Wh2,
    void* __restrict__ out) {
  __shared__ float2 aws[64 * 33];                  // 16.9 KB
  __shared__ int cs[64];
  const int f32m = detect_f32((const u32*)h);
  const int tid = threadIdx.x;
  const int s  = blockIdx.x & 7;                   // slice -> XCD (heuristic)
  const int g0 = (blockIdx.x >> 3) * 64;           // 256 groups x 64 = 16384
  const float2* awg = aw + (size_t)g0 * KCTX;
  for (int i = tid; i < 2048; i += 384) aws[(i >> 5) * 33 + (i & 31)] = awg[i];
  if (tid < 64) cs[tid] = cnt[g0 + tid];
  __syncthreads();

  const int r = tid / 6, c = tid - r * 6;          // r<64, c<6 (384 = 64*6)
  const int n = g0 + r;
  const u16* bc = Wh2 + (size_t)s * NBOX * 48 + c * 8;
  const int kc = cs[r];
  float a0 = 0, a1 = 0, a2 = 0, a3 = 0, a4 = 0, a5 = 0, a6 = 0, a7 = 0;
  for (int k = 0; k < kc; k += 4) {
    uint4 q[4]; float w4[4];
#pragma unroll
    for (int u = 0; u < 4; ++u) {                  // 4 loads in flight
      const float2 e = aws[r * 33 + k + u];
      w4[u] = e.x;
      q[u] = *(const uint4*)(bc + (size_t)((u32)__float_as_int(e.y)) * 48);
    }
#pragma unroll
    for (int u = 0; u < 4; ++u) {
      const float w = w4[u];
      a0 += w * bflo(q[u].x); a1 += w * bfhi(q[u].x);
      a2 += w * bflo(q[u].y); a3 += w * bfhi(q[u].y);
      a4 += w * bflo(q[u].z); a5 += w * bfhi(q[u].z);
      a6 += w * bflo(q[u].w); a7 += w * bfhi(q[u].w);
    }
  }
  if (f32m) {
    float4* o4 = (float4*)((float*)out + (size_t)n * HID_ + s * 48 + c * 8);
    o4[0] = (float4){a0, a1, a2, a3};
    o4[1] = (float4){a4, a5, a6, a7};
  } else {
    uint4 o;
    o.x = (u32)f2bf(a0) | ((u32)f2bf(a1) << 16);
    o.y = (u32)f2bf(a2) | ((u32)f2bf(a3) << 16);
    o.z = (u32)f2bf(a4) | ((u32)f2bf(a5) << 16);
    o.w = (u32)f2bf(a6) | ((u32)f2bf(a7) << 16);
    *(uint4*)((u16*)out + (size_t)n * HID_ + s * 48 + c * 8) = o;
  }
}

extern "C" void kernel_launch(void* const* d_in, const int* in_sizes, int n_in,
                              void* d_out, int out_size, void* d_ws, size_t ws_size,
                              hipStream_t stream) {
  const void* h  = d_in[0];
  const int*  ci = (const int*)d_in[1];
  const void* Wi = d_in[2];
  const void* Wj = d_in[3];
  const void* ai = d_in[4];
  const void* aj = d_in[5];
  const void* ab = d_in[6];

  char* ws = (char*)d_ws;
  float2* aw  = (float2*)(ws + AW_OFF);
  int*    cnt = (int*)(ws + CNT_OFF);
  u16*   Wh  = (u16*)(ws + WH_OFF);
  u16*   Bt  = (u16*)(ws + BT_OFF);
  float* v   = (float*)(ws + V_OFF);
  float* si  = (float*)(ws + SI_OFF);
  float* sj  = (float*)(ws + SJ_OFF);
  float* ajf = (float*)(ws + AJF_OFF);
  float* abf = (float*)(ws + ABF_OFF);

  prep_kernel<<<99, 256, 0, stream>>>(h, Wi, Wj, ai, aj, ab, Bt, v, ajf, abf);
  gemm_fused<<<1024, 256, 0, stream>>>(h, Bt, v, Wh, si, ajf, sj);
  score_kernel<<<2048, 256, 0, stream>>>(ci, si, sj, abf, aw, cnt);
  gather_kernel<<<2048, 384, 0, stream>>>(h, aw, cnt, Wh, d_out);
}

// Round 6
// 167.303 us; speedup vs baseline: 1.1225x; 1.1225x over previous
//
#include <hip/hip_runtime.h>
#include <hip/hip_bf16.h>

typedef unsigned short u16;
typedef unsigned int u32;
typedef __attribute__((ext_vector_type(8))) __bf16 bf16x8;
typedef __attribute__((ext_vector_type(4))) float f32x4;

#define KCTX 32
#define INF_ 608
#define HID_ 384
#define NBOX 16384

// ws layout (bytes).
#define AW_OFF  0                     // aw  [16384][32] float2 = 4,194,304
#define CNT_OFF 4194304               // cnt [16384] i32        =    65,536
#define WH_OFF  19922944              // Wh2 [8][16384][48] bf16 = 12,582,912 (slice-major)
#define BT_OFF  32505856              // Bt  [384,608]  bf16 =    466,944
#define V_OFF   32972800              // v   [608] f32        =      2,432
#define SI_OFF  32975232              // si  [16384] f32      =     65,536
#define SJ_OFF  33040768              // sj  [16384] f32      =     65,536
#define AJF_OFF 33106304              // ajf [384] f32        =      1,536
#define ABF_OFF 33107840              // abf [1] f32
#define HBF_OFF 33554432              // hbf [16384][608] bf16 = 19,922,944

__device__ __forceinline__ float bfu(u16 u)  { return __uint_as_float(((u32)u) << 16); }
__device__ __forceinline__ float bflo(u32 u) { return __uint_as_float(u << 16); }
__device__ __forceinline__ float bfhi(u32 u) { return __uint_as_float(u & 0xffff0000u); }
__device__ __forceinline__ u16 f2bf(float x) {            // round-to-nearest-even
  u32 u = __float_as_uint(x);
  return (u16)((u + 0x7fffu + ((u >> 16) & 1u)) >> 16);
}
__device__ __forceinline__ void async_ld16(const void* g, void* l) {
  __builtin_amdgcn_global_load_lds(
      (const __attribute__((address_space(1))) u32*)g,
      (__attribute__((address_space(3))) u32*)l, 16, 0, 0);
}

// ---- per-wave runtime dtype detection (wave-uniform, L2-hot; validated r2-r8) ----
__device__ __forceinline__ int detect_f32(const u32* hw) {
  const u32 w = hw[threadIdx.x & 63];
  const int e = (int)((w >> 7) & 0xffu);
  const unsigned long long mb = __ballot(e > 134 || e < 100);
  return __popcll(mb) >= 16;
}
__device__ __forceinline__ int detect_i64(const int* ci) {
  const int hi = ci[2 * (threadIdx.x & 63) + 1];
  const unsigned long long mz = __ballot(hi == 0 || hi == -1);
  return __popcll(mz) >= 48;
}

// ---- prep: Bt = bf16(W_j^T), v = W_i@a_i, ajf/abf fp32, zero sj (atomicAdd
// target in gemm v4) ----
__global__ __launch_bounds__(256) void prep_kernel(
    const void* __restrict__ h, const void* __restrict__ Wi,
    const void* __restrict__ Wj, const void* __restrict__ ai,
    const void* __restrict__ aj, const void* __restrict__ ab,
    u16* __restrict__ Bt, float* __restrict__ v, float* __restrict__ sj,
    float* __restrict__ ajf, float* __restrict__ abf) {
  __shared__ u16 tile[64][65];
  const int f32m = detect_f32((const u32*)h);
  const int bid = blockIdx.x, tid = threadIdx.x;
  if (bid < 60) {                                  // transpose: 10(f) x 6(h) tiles
    const int ft = bid / 6, ht = bid - ft * 6;
    const int f0 = ft * 64, h0 = ht * 64;
    const int ln = tid & 63, fg = tid >> 6;
#pragma unroll
    for (int rr = 0; rr < 16; ++rr) {
      const int fl = fg * 16 + rr;
      const int f = f0 + fl;
      if (f < INF_)
        tile[fl][ln] = f32m ? f2bf(((const float*)Wj)[(size_t)f * HID_ + h0 + ln])
                            : ((const u16*)Wj)[(size_t)f * HID_ + h0 + ln];
    }
    __syncthreads();
#pragma unroll
    for (int rr = 0; rr < 16; ++rr) {
      const int hl = fg * 16 + rr;
      const int f = f0 + ln;
      if (f < INF_) Bt[(size_t)(h0 + hl) * INF_ + f] = tile[ln][hl];
    }
  } else if (bid < 98) {                           // v: 16-lane group per row
    const int t = (bid - 60) * 16 + (tid >> 4);
    const int sl = tid & 15;
    if (t < INF_) {
      float s = 0.f;
      if (f32m) {
        const float4* wi = (const float4*)((const float*)Wi + (size_t)t * HID_);
        const float4* a4 = (const float4*)ai;
        for (int c = sl; c < 96; c += 16) {
          float4 x = wi[c], y = a4[c];
          s += x.x * y.x + x.y * y.y + x.z * y.z + x.w * y.w;
        }
      } else {
        const uint4* wi = (const uint4*)((const u16*)Wi + (size_t)t * HID_);
        const uint4* a4 = (const uint4*)ai;
        for (int c = sl; c < 48; c += 16) {
          uint4 x = wi[c], y = a4[c];
          s += bflo(x.x) * bflo(y.x) + bfhi(x.x) * bfhi(y.x)
             + bflo(x.y) * bflo(y.y) + bfhi(x.y) * bfhi(y.y)
             + bflo(x.z) * bflo(y.z) + bfhi(x.z) * bfhi(y.z)
             + bflo(x.w) * bflo(y.w) + bfhi(x.w) * bfhi(y.w);
        }
      }
      s += __shfl_xor(s, 1); s += __shfl_xor(s, 2);
      s += __shfl_xor(s, 4); s += __shfl_xor(s, 8);
      if (sl == 0) v[t] = s;
    }
  } else {                                         // sj zero + ajf/abf
    for (int j = tid; j < NBOX; j += 256) sj[j] = 0.f;
    for (int j = tid; j < HID_; j += 256)
      ajf[j] = f32m ? ((const float*)aj)[j] : bfu(((const u16*)aj)[j]);
    if (tid == 0)
      abf[0] = f32m ? ((const float*)ab)[0] : bfu(((const u16*)ab)[0]);
  }
}

// ---- convert: hbf = bf16(h) (f32 mode only) + si = h@v. Removes the f2bf /
// si work from gemm so gemm's A-operand can be staged by global_load_lds. ----
__global__ __launch_bounds__(256) void convert_kernel(
    const void* __restrict__ h, const float* __restrict__ v,
    u16* __restrict__ hbf, float* __restrict__ si) {
  const int f32m = detect_f32((const u32*)h);
  const int g = threadIdx.x >> 3, sub = threadIdx.x & 7;
  const int row = blockIdx.x * 32 + g;             // 512 blocks x 32 rows
  float s = 0.f;
  const float4* v4 = (const float4*)v;
  if (f32m) {
    const float4* hr = (const float4*)((const float*)h + (size_t)row * INF_);
    u32* ob = (u32*)(hbf + (size_t)row * INF_);
#pragma unroll
    for (int k = 0; k < 19; ++k) {
      const int c4 = sub + 8 * k;
      float4 x = hr[c4];
      uint2 pk;
      pk.x = (u32)f2bf(x.x) | ((u32)f2bf(x.y) << 16);
      pk.y = (u32)f2bf(x.z) | ((u32)f2bf(x.w) << 16);
      *(uint2*)&ob[c4 * 2] = pk;
      float4 w = v4[c4];
      s += x.x * w.x + x.y * w.y + x.z * w.z + x.w * w.w;
    }
  } else {
    const uint4* hr = (const uint4*)((const u16*)h + (size_t)row * INF_);
    for (int k = 0; k < 10; ++k) {
      const int c8 = sub + 8 * k;
      if (c8 < 76) {
        uint4 x = hr[c8];
        float4 w0 = v4[2 * c8], w1 = v4[2 * c8 + 1];
        s += bflo(x.x) * w0.x + bfhi(x.x) * w0.y + bflo(x.y) * w0.z + bfhi(x.y) * w0.w
           + bflo(x.z) * w1.x + bfhi(x.z) * w1.y + bflo(x.w) * w1.z + bfhi(x.w) * w1.w;
      }
    }
  }
  s += __shfl_xor(s, 1); s += __shfl_xor(s, 2); s += __shfl_xor(s, 4);
  if (sub == 0) si[row] = s;
}

// ---- gemm v4: ZERO-barrier wave-private pipeline. r1/r2 failed on the
// block-wide vmcnt(0)+barrier drain (nothing co-resident to cover it); r5
// failed on raw gather latency. Here each WAVE owns a 64x96 tile and its own
// LDS double-buffer (A 4KB + B 6KB per buf), staged via global_load_lds and
// synced ONLY by counted per-wave s_waitcnt vmcnt(10): the next step's 10
// DMAs are always in flight while the current step's 24 MFMAs run. No
// __syncthreads anywhere. 256 blocks (1/CU) x 4 waves; block = 256 rows x
// 96-col panel; grid split panel=bid>>6 so each XCD's A slice (2.5 MB) +
// Bt (467 KB) are L2-resident. Per-CU L2 traffic ~760 KB -> ~6 us floor. ----
__global__ __launch_bounds__(256) void gemm_fused(
    const void* __restrict__ A, const u16* __restrict__ hbf_,
    const u16* __restrict__ Bt, u16* __restrict__ C,
    const float* __restrict__ ajf, float* __restrict__ sj) {
  extern __shared__ __align__(16) char smem[];     // 4 waves x 2 bufs x 10240
  const int f32m = detect_f32((const u32*)A);
  const int tid  = threadIdx.x;
  const int lane = tid & 63;
  const int wv   = tid >> 6;                       // 0..3
  const int lm   = lane & 15, q = lane >> 4;
  const int panel = blockIdx.x >> 6;               // 0..3 (96-col panel)
  const int rowc  = blockIdx.x & 63;               // 0..63 (256-row chunk)
  const int row0 = rowc * 256 + wv * 64;           // wave's 64 rows
  const int c0   = panel * 96;                     // wave's 96 cols (all waves)
  const char* hB = f32m ? (const char*)hbf_ : (const char*)A;   // bf16 rows, 1216 B
  const char* hrow = hB + (size_t)(row0 + (lane >> 2)) * 1216 + (lane & 3) * 16;
  const char* brow = (const char*)Bt + (size_t)(c0 + (lane >> 2)) * 1216 + (lane & 3) * 16;
  char* wbase = smem + wv * 20480;

  f32x4 acc[4][6];
#pragma unroll
  for (int mf = 0; mf < 4; ++mf)
#pragma unroll
    for (int nf = 0; nf < 6; ++nf) acc[mf][nf] = (f32x4){0.f, 0.f, 0.f, 0.f};

  // prologue: stage kt=0 into buf0 (10 DMAs: A 4x1KB rows-of-16, B 6x1KB)
#pragma unroll
  for (int i = 0; i < 4; ++i)
    async_ld16(hrow + i * 19456, wbase + i * 1024 + lane * 16);
#pragma unroll
  for (int i = 0; i < 6; ++i)
    async_ld16(brow + i * 19456, wbase + 4096 + i * 1024 + lane * 16);

  int cur = 0;
  for (int kt = 0; kt < 19; ++kt) {
    if (kt < 18) {                                 // stage kt+1 into buf^1
      const int kb = (kt + 1) * 64;
      char* nb = wbase + (cur ^ 1) * 10240;
#pragma unroll
      for (int i = 0; i < 4; ++i)
        async_ld16(hrow + i * 19456 + kb, nb + i * 1024 + lane * 16);
#pragma unroll
      for (int i = 0; i < 6; ++i)
        async_ld16(brow + i * 19456 + kb, nb + 4096 + i * 1024 + lane * 16);
      asm volatile("s_waitcnt vmcnt(10)" ::: "memory");  // batch kt complete
    } else {
      asm volatile("s_waitcnt vmcnt(0)" ::: "memory");   // last batch complete
    }
    __builtin_amdgcn_sched_barrier(0);             // rule 18: pin ds_reads below
    const char* ab = wbase + cur * 10240;
    const char* bb = ab + 4096;
    bf16x8 af[4], bfr[6];
#pragma unroll
    for (int mf = 0; mf < 4; ++mf)
      af[mf] = *(const bf16x8*)(ab + (mf * 16 + lm) * 64 + q * 16);
#pragma unroll
    for (int nf = 0; nf < 6; ++nf)
      bfr[nf] = *(const bf16x8*)(bb + (nf * 16 + lm) * 64 + q * 16);
#pragma unroll
    for (int mf = 0; mf < 4; ++mf)
#pragma unroll
      for (int nf = 0; nf < 6; ++nf)
        acc[mf][nf] = __builtin_amdgcn_mfma_f32_16x16x32_bf16(
            af[mf], bfr[nf], acc[mf][nf], 0, 0, 0);
    cur ^= 1;
  }

  // epilogue: C slice-major (Wh2[s][row][48]) + sj (4 panel-blocks atomicAdd)
  float ajv[6];
#pragma unroll
  for (int nf = 0; nf < 6; ++nf) ajv[nf] = ajf[c0 + nf * 16 + lm];
#pragma unroll
  for (int mf = 0; mf < 4; ++mf) {
#pragma unroll
    for (int nf = 0; nf < 6; ++nf) {
      const int colp = nf * 16 + lm;
      const int s  = panel * 2 + (colp >= 48 ? 1 : 0);
      const int cw = colp >= 48 ? colp - 48 : colp;
#pragma unroll
      for (int r = 0; r < 4; ++r) {
        const int rowg = row0 + mf * 16 + q * 4 + r;
        C[((size_t)s * NBOX + rowg) * 48 + cw] = f2bf(acc[mf][nf][r]);
      }
    }
#pragma unroll
    for (int r = 0; r < 4; ++r) {
      float p = acc[mf][0][r] * ajv[0] + acc[mf][1][r] * ajv[1]
              + acc[mf][2][r] * ajv[2] + acc[mf][3][r] * ajv[3]
              + acc[mf][4][r] * ajv[4] + acc[mf][5][r] * ajv[5];
      p += __shfl_xor(p, 1); p += __shfl_xor(p, 2);
      p += __shfl_xor(p, 4); p += __shfl_xor(p, 8);
      if (lm == 0) atomicAdd(&sj[row0 + mf * 16 + q * 4 + r], p);
    }
  }
}

// ---- score: softmax weights once per row, compacted (ballot prefix),
// padded to multiple of 4 with (w=0, idx=0). 2048 blocks x 256 thr, 8 rows/blk. ----
__global__ __launch_bounds__(256) void score_kernel(
    const int* __restrict__ ci, const float* __restrict__ si,
    const float* __restrict__ sj, const float* __restrict__ abf,
    float2* __restrict__ aw, int* __restrict__ cnt) {
  const int i64 = detect_i64(ci);
  const int tid = threadIdx.x;
  const int k = tid & 31;
  const int n = blockIdx.x * 8 + (tid >> 5);       // 2048*8 = 16384 exactly
  const size_t t = (size_t)n * KCTX + k;
  int idx;
  if (i64) { int lo = ci[2 * t], hi2 = ci[2 * t + 1]; idx = (hi2 < 0) ? -1 : lo; }
  else     { idx = ci[t]; }
  const bool valid = idx >= 0;
  const float sjv = valid ? sj[idx] : 0.f;
  float raw = si[n] + sjv + abf[0];
  float lr = raw > 0.f ? raw : 0.2f * raw;
  float s = valid ? lr : -9e15f;
  float m = s;
#pragma unroll
  for (int o = 16; o; o >>= 1) m = fmaxf(m, __shfl_xor(m, o, 32));
  float p = __expf(s - m);
  float d = p;
#pragma unroll
  for (int o = 16; o; o >>= 1) d += __shfl_xor(d, o, 32);
  const float w = p / d;                           // invalid: p==0 => w==0
  const unsigned long long bm = __ballot(valid);
  const u32 m32 = (u32)(bm >> (tid & 32));         // this 32-group's mask
  const int c_ = __popc(m32);
  const int r4 = (c_ + 3) & ~3;                    // pad to multiple of 4
  if (valid) {
    const int pf = __popc(m32 & ((1u << k) - 1u));
    aw[(size_t)n * KCTX + pf] = (float2){w, __int_as_float(idx)};
  }
  if (k >= c_ && k < r4) aw[(size_t)n * KCTX + k] = (float2){0.f, 0.f};
  if (k == 0) cnt[n] = r4;
}

// ---- gather: XCD-partitioned slices (r4, unchanged). 2048 blocks x 384 thr;
// slice s = blockIdx&7, rows g0..g0+63; each block reads only Wh2[s]
// (1.57 MB, per-XCD-L2-resident). ----
__global__ __launch_bounds__(384) void gather_kernel(
    const void* __restrict__ h, const float2* __restrict__ aw,
    const int* __restrict__ cnt, const u16* __restrict__ Wh2,
    void* __restrict__ out) {
  __shared__ float2 aws[64 * 33];                  // 16.9 KB
  __shared__ int cs[64];
  const int f32m = detect_f32((const u32*)h);
  const int tid = threadIdx.x;
  const int s  = blockIdx.x & 7;                   // slice -> XCD (heuristic)
  const int g0 = (blockIdx.x >> 3) * 64;           // 256 groups x 64 = 16384
  const float2* awg = aw + (size_t)g0 * KCTX;
  for (int i = tid; i < 2048; i += 384) aws[(i >> 5) * 33 + (i & 31)] = awg[i];
  if (tid < 64) cs[tid] = cnt[g0 + tid];
  __syncthreads();

  const int r = tid / 6, c = tid - r * 6;          // r<64, c<6 (384 = 64*6)
  const int n = g0 + r;
  const u16* bc = Wh2 + (size_t)s * NBOX * 48 + c * 8;
  const int kc = cs[r];
  float a0 = 0, a1 = 0, a2 = 0, a3 = 0, a4 = 0, a5 = 0, a6 = 0, a7 = 0;
  for (int k = 0; k < kc; k += 4) {
    uint4 q[4]; float w4[4];
#pragma unroll
    for (int u = 0; u < 4; ++u) {                  // 4 loads in flight
      const float2 e = aws[r * 33 + k + u];
      w4[u] = e.x;
      q[u] = *(const uint4*)(bc + (size_t)((u32)__float_as_int(e.y)) * 48);
    }
#pragma unroll
    for (int u = 0; u < 4; ++u) {
      const float w = w4[u];
      a0 += w * bflo(q[u].x); a1 += w * bfhi(q[u].x);
      a2 += w * bflo(q[u].y); a3 += w * bfhi(q[u].y);
      a4 += w * bflo(q[u].z); a5 += w * bfhi(q[u].z);
      a6 += w * bflo(q[u].w); a7 += w * bfhi(q[u].w);
    }
  }
  if (f32m) {
    float4* o4 = (float4*)((float*)out + (size_t)n * HID_ + s * 48 + c * 8);
    o4[0] = (float4){a0, a1, a2, a3};
    o4[1] = (float4){a4, a5, a6, a7};
  } else {
    uint4 o;
    o.x = (u32)f2bf(a0) | ((u32)f2bf(a1) << 16);
    o.y = (u32)f2bf(a2) | ((u32)f2bf(a3) << 16);
    o.z = (u32)f2bf(a4) | ((u32)f2bf(a5) << 16);
    o.w = (u32)f2bf(a6) | ((u32)f2bf(a7) << 16);
    *(uint4*)((u16*)out + (size_t)n * HID_ + s * 48 + c * 8) = o;
  }
}

extern "C" void kernel_launch(void* const* d_in, const int* in_sizes, int n_in,
                              void* d_out, int out_size, void* d_ws, size_t ws_size,
                              hipStream_t stream) {
  const void* h  = d_in[0];
  const int*  ci = (const int*)d_in[1];
  const void* Wi = d_in[2];
  const void* Wj = d_in[3];
  const void* ai = d_in[4];
  const void* aj = d_in[5];
  const void* ab = d_in[6];

  char* ws = (char*)d_ws;
  float2* aw  = (float2*)(ws + AW_OFF);
  int*    cnt = (int*)(ws + CNT_OFF);
  u16*   Wh  = (u16*)(ws + WH_OFF);
  u16*   Bt  = (u16*)(ws + BT_OFF);
  float* v   = (float*)(ws + V_OFF);
  float* si  = (float*)(ws + SI_OFF);
  float* sj  = (float*)(ws + SJ_OFF);
  float* ajf = (float*)(ws + AJF_OFF);
  float* abf = (float*)(ws + ABF_OFF);
  u16*   hbf = (u16*)(ws + HBF_OFF);

  prep_kernel<<<99, 256, 0, stream>>>(h, Wi, Wj, ai, aj, ab, Bt, v, sj, ajf, abf);
  convert_kernel<<<512, 256, 0, stream>>>(h, v, hbf, si);
  gemm_fused<<<256, 256, 81920, stream>>>(h, hbf, Bt, Wh, ajf, sj);
  score_kernel<<<2048, 256, 0, stream>>>(ci, si, sj, abf, aw, cnt);
  gather_kernel<<<2048, 384, 0, stream>>>(h, aw, cnt, Wh, d_out);
}